// Round 11
// baseline (202.149 us; speedup 1.0000x reference)
//
#include <hip/hip_runtime.h>

// Tree-LSTM AST encoder, complete 8-ary tree, N=100000, D=128, C=8.
// Internal nodes 0..12499 (only 12499 has 7 children -> masked at s==8),
// leaves 12500..99999 (leaf result == emb row), sentinel 100000.
//
// R10 post-mortem: intra-dispatch cross-block handoff (RELEASE arrive /
// RELAXED spin / one fence) produced stale reads (absmax 2e-2) -> hand-rolled
// grid barriers are BANNED this session. Only proven orderings are used:
//   (a) kernel-boundary ordering between dispatches,
//   (b) same-block sequential execution (block reads its own writes).
//
// Structure: 4 dispatches, no barriers, no memset:
//   L5 [4681,12500) 245 blks | L4 [585,4681) 128 | L3 [73,585) 16
//   | TAIL (1 block): L2 tile {9..40}, L2 tile {41..72}, L1 {1..8}, root {0}.
//
// Per block: 8 waves; wave w owns dims w*16..+15 for all 4 gates; cell fully
// in registers from MFMA C/D frags (col=lane&15, row=(lane>>4)*4+reg).
// Weight B-fragments built from fp32 W, PINNED into AGPRs via asm (cannot be
// remat'd or spilled; R6/R7 lesson): 128 AGPR + ~120 VGPR @ 2 waves/SIMD.
// Double-buffered Xh, one intra-block barrier per step, 2-step gather prefetch.
//
// ws: resultsH f16[12500*128] (3.2MB)

#define D 128
#define NTOT 100000
#define NINT 12500

typedef _Float16 f16x8 __attribute__((ext_vector_type(8)));
typedef float    f32x4 __attribute__((ext_vector_type(4)));

__device__ __forceinline__ float fsig(float x) {
    return __builtin_amdgcn_rcpf(1.f + __expf(-x));
}
__device__ __forceinline__ float ftanh(float x) {
    return 1.f - 2.f * __builtin_amdgcn_rcpf(__expf(2.f * x) + 1.f);
}

// B operand pinned in AGPRs; asm-defined values cannot be rematerialized.
#define MFMA_AB(ACC, A, B) \
    asm("v_mfma_f32_16x16x32_f16 %0, %1, %2, %0" : "+v"(ACC) : "v"(A), "a"(B))
#define PIN_AGPR(X) asm("" : "+a"(X))

template<bool TAIL>
__global__ __launch_bounds__(512) void lstm_level(
    int start, int count, int l5chk,
    const float* __restrict__ W_ih, const float* __restrict__ W_hh,
    const float* __restrict__ b_ih, const float* __restrict__ b_hh,
    const float* __restrict__ emb, const int* __restrict__ node_types,
    const int* __restrict__ children,
    _Float16* __restrict__ resultsH, float* __restrict__ out)
{
    __shared__ __align__(16) _Float16 Xh[2][32][264];  // [buf][node][x(128)|h(128)|pad]
    __shared__ int chid_s[32][8];
    __shared__ int chty_s[32][8];

    const int t    = threadIdx.x;
    const int w    = t >> 6;
    const int l    = t & 63;
    const int bid  = blockIdx.x;
    const int row  = t >> 4;           // gather row (TPR=16)
    const int di   = (t & 15) * 8;     // gather dim offset (DPT=8)
    const int dcol = w * 16 + (l & 15);

    // ---- weight B-fragments straight from fp32 W; PINNED into AGPRs ----
    // frag(ct,kk): k0=(kk&3)*32+(l>>4)*8, c=ct*128+dcol; B[k][c]=W[c][k]
    f16x8 bf[4][8];
#pragma unroll
    for (int ct = 0; ct < 4; ++ct) {
        const int c = ct * 128 + dcol;
#pragma unroll
        for (int kk = 0; kk < 8; ++kk) {
            const int k0 = (kk & 3) * 32 + ((l >> 4) * 8);
            const float* src = (kk < 4) ? (W_ih + (size_t)c * D + k0)
                                        : (W_hh + (size_t)c * D + k0);
            float4 a = *(const float4*)(src);
            float4 b = *(const float4*)(src + 4);
            f16x8 v;
            v[0]=(_Float16)a.x; v[1]=(_Float16)a.y; v[2]=(_Float16)a.z; v[3]=(_Float16)a.w;
            v[4]=(_Float16)b.x; v[5]=(_Float16)b.y; v[6]=(_Float16)b.z; v[7]=(_Float16)b.w;
            bf[ct][kk] = v;
            PIN_AGPR(bf[ct][kk]);
        }
    }
    float4 bb;
    bb.x = b_ih[dcol      ] + b_hh[dcol      ];
    bb.y = b_ih[dcol + 128] + b_hh[dcol + 128];
    bb.z = b_ih[dcol + 256] + b_hh[dcol + 256];
    bb.w = b_ih[dcol + 384] + b_hh[dcol + 384];

    float cr[2][4], hr[2][4];
    f32x4 acc[2][4];

    auto embf = [&](int ty) -> f16x8 {
        const float* p = emb + (size_t)ty * D + di;
        float4 a = *(const float4*)p;
        float4 b = *(const float4*)(p + 4);
        f16x8 v;
        v[0]=(_Float16)a.x; v[1]=(_Float16)a.y; v[2]=(_Float16)a.z; v[3]=(_Float16)a.w;
        v[4]=(_Float16)b.x; v[5]=(_Float16)b.y; v[6]=(_Float16)b.z; v[7]=(_Float16)b.w;
        return v;
    };

    auto do_tile = [&](int n0, int B, bool chk, bool wres, bool wout) {
        if (t < 256) {
            int rr = t >> 3, slot = t & 7;
            int ch = children[(size_t)(n0 + rr) * 8 + slot];
            chid_s[rr][slot] = ch;
            chty_s[rr][slot] = (ch >= NINT && ch < NTOT) ? node_types[ch] : 0;
        }
        __syncthreads();

        auto gath = [&](int s) -> f16x8 {
            if (s == 0) return embf(node_types[n0 + row]);
            int ch = chid_s[row][s - 1];
            if (ch >= NTOT) return (f16x8)(_Float16)0.f;
            if (ch < NINT)  return *(const f16x8*)(resultsH + (size_t)ch * D + di);
            return embf(chty_s[row][s - 1]);
        };

        *(f16x8*)&Xh[0][row][di]       = gath(0);
        *(f16x8*)&Xh[0][row][128 + di] = (f16x8)(_Float16)0.f;
        f16x8 xA = gath(1);
        f16x8 xB = gath(2);
#pragma unroll
        for (int rt = 0; rt < 2; ++rt)
#pragma unroll
            for (int r = 0; r < 4; ++r) { cr[rt][r] = 0.f; hr[rt][r] = 0.f; }
        __syncthreads();

        for (int s = 0; s < 9; ++s) {
            const int b = s & 1;
            // MFMA: gates[32x512] = Xh[32x256] * Wcat[256x512]
#pragma unroll
            for (int rt = 0; rt < 2; ++rt)
#pragma unroll
                for (int ct = 0; ct < 4; ++ct) acc[rt][ct] = (f32x4){0.f, 0.f, 0.f, 0.f};
#pragma unroll
            for (int kk = 0; kk < 8; ++kk) {
#pragma unroll
                for (int rt = 0; rt < 2; ++rt) {
                    f16x8 a = *(const f16x8*)&Xh[b][rt * 16 + (l & 15)][kk * 32 + ((l >> 4) * 8)];
#pragma unroll
                    for (int ct = 0; ct < 4; ++ct)
                        MFMA_AB(acc[rt][ct], a, bf[ct][kk]);
                }
            }
            if (s < 8) {
                *(f16x8*)&Xh[b ^ 1][row][di] = xA;
                xA = xB;
                if (s <= 5) xB = gath(s + 3);
            }
            // cell fully in registers
#pragma unroll
            for (int rt = 0; rt < 2; ++rt)
#pragma unroll
                for (int r = 0; r < 4; ++r) {
                    const int r2 = rt * 16 + ((l >> 4) * 4) + r;
                    const bool upd = !chk || s < 8 || (n0 + r2 != NINT - 1);
                    if (upd) {
                        float iv = fsig (acc[rt][0][r] + bb.x);
                        float fv = fsig (acc[rt][1][r] + bb.y);
                        float gv = ftanh(acc[rt][2][r] + bb.z);
                        float ov = fsig (acc[rt][3][r] + bb.w);
                        float cn = fv * cr[rt][r] + iv * gv;
                        cr[rt][r] = cn;
                        hr[rt][r] = ov * ftanh(cn);
                    }
                    if (s < 8) Xh[b ^ 1][r2][128 + dcol] = (_Float16)hr[rt][r];
                }
            __syncthreads();
        }

#pragma unroll
        for (int rt = 0; rt < 2; ++rt)
#pragma unroll
            for (int r = 0; r < 4; ++r) {
                const int r2 = rt * 16 + ((l >> 4) * 4) + r;
                if (wres && r2 < B)
                    resultsH[(size_t)(n0 + r2) * D + dcol] = (_Float16)hr[rt][r];
            }
        if (wout && (l >> 4) == 0) out[dcol] = hr[0][0];
    };

    if constexpr (!TAIL) {
        // one 32-node tile per block
        int n0 = start + bid * 32;
        if (n0 < start + count)
            do_tile(n0, min(32, start + count - n0), l5chk != 0, true, false);
    } else {
        // single block, fully block-local (reads only its own prior writes
        // within this dispatch; L3 results come via kernel boundary)
        do_tile( 9, 32, false, true,  false);   // L2 tile 0: nodes 9..40
        do_tile(41, 32, false, true,  false);   // L2 tile 1: nodes 41..72
        do_tile( 1,  8, false, true,  false);   // L1: nodes 1..8
        do_tile( 0,  1, false, false, true);    // root: node 0 -> out
    }
}

extern "C" void kernel_launch(void* const* d_in, const int* in_sizes, int n_in,
                              void* d_out, int out_size, void* d_ws, size_t ws_size,
                              hipStream_t stream)
{
    const float* emb        = (const float*)d_in[0];
    const float* W_ih       = (const float*)d_in[1];
    const float* W_hh       = (const float*)d_in[2];
    const float* b_ih       = (const float*)d_in[3];
    const float* b_hh       = (const float*)d_in[4];
    const int*   node_types = (const int*)d_in[5];
    const int*   children   = (const int*)d_in[6];

    float*    out      = (float*)d_out;
    _Float16* resultsH = (_Float16*)d_ws;    // 3.2 MB

    // L5: 7819 nodes, 245 blocks
    lstm_level<false><<<245, 512, 0, stream>>>(4681, 7819, 1,
        W_ih, W_hh, b_ih, b_hh, emb, node_types, children, resultsH, out);
    // L4: 4096 nodes, 128 blocks
    lstm_level<false><<<128, 512, 0, stream>>>(585, 4096, 0,
        W_ih, W_hh, b_ih, b_hh, emb, node_types, children, resultsH, out);
    // L3: 512 nodes, 16 blocks
    lstm_level<false><<<16, 512, 0, stream>>>(73, 512, 0,
        W_ih, W_hh, b_ih, b_hh, emb, node_types, children, resultsH, out);
    // TAIL: L2 (2 tiles) + L1 + root, one block, block-local
    lstm_level<true><<<1, 512, 0, stream>>>(0, 0, 0,
        W_ih, W_hh, b_ih, b_hh, emb, node_types, children, resultsH, out);
}

// Round 12
// 164.490 us; speedup vs baseline: 1.2289x; 1.2289x over previous
//
#include <hip/hip_runtime.h>

// Tree-LSTM AST encoder, complete 8-ary tree, N=100000, D=128, C=8.
// Internal nodes 0..12499 (only 12499 has 7 children -> masked at s==8),
// leaves 12500..99999 (leaf result == emb row), sentinel 100000.
//
// R11 cost model (measured): per-tile-pass time scales with cells/lane
// (RT2 32-node pass ~23us, RT1 16-node pass ~9-11us; VALU/transcendental
// issue-bound cell phase). Total ~= sum of per-pass costs along the
// sequential chain. So: cheapest pass type per level, blocks <= 256:
//   L5 [4681,12500) RT2 x245 blks | L4 [585,4681) RT1 x256 | L3 [73,585) RT1 x32
//   | L2 [9,73) RT1 x4 | L1 [1,9) + root fused, 1 block (Hstash in LDS).
// 5 dispatches; cross-level visibility by kernel boundary ONLY (hand-rolled
// grid barriers banned after R10's stale-read failure).
//
// Per block: 8 waves; wave w owns dims w*16..+15 for all 4 gates; cell fully
// in registers from MFMA C/D frags (col=lane&15, row=(lane>>4)*4+reg).
// Weight B-fragments built from fp32 W, PINNED into AGPRs via asm (cannot be
// remat'd or spilled; R6/R7 lesson): 128 AGPR + ~120 VGPR @ 2 waves/SIMD.
// Double-buffered Xh, one intra-block barrier/step, 2-step gather prefetch.
//
// ws: resultsH f16[12500*128] (3.2MB)

#define D 128
#define NTOT 100000
#define NINT 12500

typedef _Float16 f16x8 __attribute__((ext_vector_type(8)));
typedef _Float16 f16x4 __attribute__((ext_vector_type(4)));
typedef float    f32x4 __attribute__((ext_vector_type(4)));

__device__ __forceinline__ float fsig(float x) {
    return __builtin_amdgcn_rcpf(1.f + __expf(-x));
}
__device__ __forceinline__ float ftanh(float x) {
    return 1.f - 2.f * __builtin_amdgcn_rcpf(__expf(2.f * x) + 1.f);
}

// B operand pinned in AGPRs; asm-defined values cannot be rematerialized.
#define MFMA_AB(ACC, A, B) \
    asm("v_mfma_f32_16x16x32_f16 %0, %1, %2, %0" : "+v"(ACC) : "v"(A), "a"(B))
#define PIN_AGPR(X) asm("" : "+a"(X))

template<int DPT> struct XVT;
template<> struct XVT<8> { using T = f16x8; };
template<> struct XVT<4> { using T = f16x4; };

template<int RT, bool FUSE>
__global__ __launch_bounds__(512) void lstm_level(
    int start, int count, int chk,
    const float* __restrict__ W_ih, const float* __restrict__ W_hh,
    const float* __restrict__ b_ih, const float* __restrict__ b_hh,
    const float* __restrict__ emb, const int* __restrict__ node_types,
    const int* __restrict__ children,
    _Float16* __restrict__ resultsH, float* __restrict__ out)
{
    constexpr int NR  = 16 * RT;       // nodes per tile
    constexpr int TPR = 512 / NR;      // threads per row (gather)
    constexpr int DPT = 128 / TPR;     // dims per thread (gather)
    using xvec = typename XVT<DPT>::T;

    __shared__ __align__(16) _Float16 Xh[2][NR][264];  // [buf][node][x|h|pad]
    __shared__ int chid_s[NR][8];
    __shared__ int chty_s[NR][8];
    __shared__ __align__(16) _Float16 Hstash[8][128];

    const int t    = threadIdx.x;
    const int w    = t >> 6;
    const int l    = t & 63;
    const int bid  = blockIdx.x;
    const int row  = t / TPR;
    const int di   = (t % TPR) * DPT;
    const int dcol = w * 16 + (l & 15);

    // ---- weight B-fragments straight from fp32 W; PINNED into AGPRs ----
    // frag(ct,kk): k0=(kk&3)*32+(l>>4)*8, c=ct*128+dcol; B[k][c]=W[c][k]
    f16x8 bf[4][8];
#pragma unroll
    for (int ct = 0; ct < 4; ++ct) {
        const int c = ct * 128 + dcol;
#pragma unroll
        for (int kk = 0; kk < 8; ++kk) {
            const int k0 = (kk & 3) * 32 + ((l >> 4) * 8);
            const float* src = (kk < 4) ? (W_ih + (size_t)c * D + k0)
                                        : (W_hh + (size_t)c * D + k0);
            float4 a = *(const float4*)(src);
            float4 b = *(const float4*)(src + 4);
            f16x8 v;
            v[0]=(_Float16)a.x; v[1]=(_Float16)a.y; v[2]=(_Float16)a.z; v[3]=(_Float16)a.w;
            v[4]=(_Float16)b.x; v[5]=(_Float16)b.y; v[6]=(_Float16)b.z; v[7]=(_Float16)b.w;
            bf[ct][kk] = v;
            PIN_AGPR(bf[ct][kk]);
        }
    }
    float4 bb;
    bb.x = b_ih[dcol      ] + b_hh[dcol      ];
    bb.y = b_ih[dcol + 128] + b_hh[dcol + 128];
    bb.z = b_ih[dcol + 256] + b_hh[dcol + 256];
    bb.w = b_ih[dcol + 384] + b_hh[dcol + 384];

    float cr[RT][4], hr[RT][4];
    f32x4 acc[RT][4];

    auto embf = [&](int ty) -> xvec {
        const float* p = emb + (size_t)ty * D + di;
        xvec v;
#pragma unroll
        for (int q = 0; q < DPT; q += 4) {
            float4 a = *(const float4*)(p + q);
            v[q+0]=(_Float16)a.x; v[q+1]=(_Float16)a.y;
            v[q+2]=(_Float16)a.z; v[q+3]=(_Float16)a.w;
        }
        return v;
    };

    auto mfma_phase = [&](int b) {
#pragma unroll
        for (int rt = 0; rt < RT; ++rt)
#pragma unroll
            for (int ct = 0; ct < 4; ++ct) acc[rt][ct] = (f32x4){0.f, 0.f, 0.f, 0.f};
#pragma unroll
        for (int kk = 0; kk < 8; ++kk) {
#pragma unroll
            for (int rt = 0; rt < RT; ++rt) {
                f16x8 a = *(const f16x8*)&Xh[b][rt * 16 + (l & 15)][kk * 32 + ((l >> 4) * 8)];
#pragma unroll
                for (int ct = 0; ct < 4; ++ct)
                    MFMA_AB(acc[rt][ct], a, bf[ct][kk]);
            }
        }
    };

    auto cell_phase = [&](int s, int b, bool always, int n0) {
#pragma unroll
        for (int rt = 0; rt < RT; ++rt)
#pragma unroll
            for (int r = 0; r < 4; ++r) {
                const int r2 = rt * 16 + ((l >> 4) * 4) + r;
                const bool upd = always ||
                    ((s == 0 || chid_s[r2][s - 1] < NTOT) &&
                     (!chk || s < 8 || (n0 + r2 != NINT - 1)));
                if (upd) {
                    float iv = fsig (acc[rt][0][r] + bb.x);
                    float fv = fsig (acc[rt][1][r] + bb.y);
                    float gv = ftanh(acc[rt][2][r] + bb.z);
                    float ov = fsig (acc[rt][3][r] + bb.w);
                    float cn = fv * cr[rt][r] + iv * gv;
                    cr[rt][r] = cn;
                    hr[rt][r] = ov * ftanh(cn);
                }
                if (s < 8) Xh[b ^ 1][r2][128 + dcol] = (_Float16)hr[rt][r];
            }
    };

    auto do_tile = [&](int n0, int B, bool wres, bool stash) {
        if (t < NR * 8) {
            int rr = t >> 3, slot = t & 7;
            int ch = children[(size_t)(n0 + rr) * 8 + slot];
            chid_s[rr][slot] = ch;
            chty_s[rr][slot] = (ch >= NINT && ch < NTOT) ? node_types[ch] : 0;
        }
        __syncthreads();

        auto gath = [&](int s) -> xvec {
            if (s == 0) return embf(node_types[n0 + row]);
            int ch = chid_s[row][s - 1];
            if (ch >= NTOT) return (xvec)(_Float16)0.f;
            if (ch < NINT)  return *(const xvec*)(resultsH + (size_t)ch * D + di);
            return embf(chty_s[row][s - 1]);
        };

        *(xvec*)&Xh[0][row][di]       = gath(0);
        *(xvec*)&Xh[0][row][128 + di] = (xvec)(_Float16)0.f;
        xvec xA = gath(1);
        xvec xB = gath(2);
#pragma unroll
        for (int rt = 0; rt < RT; ++rt)
#pragma unroll
            for (int r = 0; r < 4; ++r) { cr[rt][r] = 0.f; hr[rt][r] = 0.f; }
        __syncthreads();

        for (int s = 0; s < 9; ++s) {
            const int b = s & 1;
            mfma_phase(b);
            if (s < 8) {
                *(xvec*)&Xh[b ^ 1][row][di] = xA;
                xA = xB;
                if (s <= 5) xB = gath(s + 3);
            }
            cell_phase(s, b, false, n0);
            __syncthreads();
        }

#pragma unroll
        for (int rt = 0; rt < RT; ++rt)
#pragma unroll
            for (int r = 0; r < 4; ++r) {
                const int r2 = rt * 16 + ((l >> 4) * 4) + r;
                if (r2 < B) {
                    if (wres) resultsH[(size_t)(n0 + r2) * D + dcol] = (_Float16)hr[rt][r];
                    if (stash && r2 < 8) Hstash[r2][dcol] = (_Float16)hr[rt][r];
                }
            }
    };

    // ---- this dispatch's level: one tile per block ----
    {
        int n0 = start + bid * NR;
        if (n0 < start + count)
            do_tile(n0, min(NR, start + count - n0), true, FUSE);
    }

    // ---- fused root pass (FUSE dispatch = L1 nodes 1..8 in 1 block) ----
    if constexpr (FUSE) {
        __syncthreads();   // Hstash visible; all reads of Xh done
        *(xvec*)&Xh[0][row][di]       = embf(node_types[0]);
        *(xvec*)&Xh[0][row][128 + di] = (xvec)(_Float16)0.f;
#pragma unroll
        for (int rt = 0; rt < RT; ++rt)
#pragma unroll
            for (int r = 0; r < 4; ++r) { cr[rt][r] = 0.f; hr[rt][r] = 0.f; }
        __syncthreads();

        for (int s = 0; s < 9; ++s) {
            const int b = s & 1;
            mfma_phase(b);
            if (s < 8)
                *(xvec*)&Xh[b ^ 1][row][di] = *(const xvec*)&Hstash[s][di];
            cell_phase(s, b, true, 0);
            __syncthreads();
        }
        if ((l >> 4) == 0) out[dcol] = hr[0][0];
    }
}

extern "C" void kernel_launch(void* const* d_in, const int* in_sizes, int n_in,
                              void* d_out, int out_size, void* d_ws, size_t ws_size,
                              hipStream_t stream)
{
    const float* emb        = (const float*)d_in[0];
    const float* W_ih       = (const float*)d_in[1];
    const float* W_hh       = (const float*)d_in[2];
    const float* b_ih       = (const float*)d_in[3];
    const float* b_hh       = (const float*)d_in[4];
    const int*   node_types = (const int*)d_in[5];
    const int*   children   = (const int*)d_in[6];

    float*    out      = (float*)d_out;
    _Float16* resultsH = (_Float16*)d_ws;    // 3.2 MB

    // L5: 7819 nodes, RT2 (32-node tiles), 245 blocks; node 12499 mask on
    lstm_level<2,false><<<245, 512, 0, stream>>>(4681, 7819, 1,
        W_ih, W_hh, b_ih, b_hh, emb, node_types, children, resultsH, out);
    // L4: 4096 nodes, RT1, 256 blocks
    lstm_level<1,false><<<256, 512, 0, stream>>>(585, 4096, 0,
        W_ih, W_hh, b_ih, b_hh, emb, node_types, children, resultsH, out);
    // L3: 512 nodes, RT1, 32 blocks
    lstm_level<1,false><<<32, 512, 0, stream>>>(73, 512, 0,
        W_ih, W_hh, b_ih, b_hh, emb, node_types, children, resultsH, out);
    // L2: 64 nodes, RT1, 4 blocks
    lstm_level<1,false><<<4, 512, 0, stream>>>(9, 64, 0,
        W_ih, W_hh, b_ih, b_hh, emb, node_types, children, resultsH, out);
    // L1 (nodes 1..8) + root fused, 1 block, Hstash handoff in LDS
    lstm_level<1,true><<<1, 512, 0, stream>>>(1, 8, 0,
        W_ih, W_hh, b_ih, b_hh, emb, node_types, children, resultsH, out);
}